// Round 1
// baseline (345.346 us; speedup 1.0000x reference)
//
#include <hip/hip_runtime.h>
#include <stdint.h>

#define N_MEM   50000
#define DDIM    1024
#define MQ      256
#define BK      64
#define NT      64
#define NCHUNK  ((N_MEM + NT - 1) / NT)   // 782
#define KCHUNKS (DDIM / BK)               // 16
#define THREADS 256
#define SIM_TH  0.6f
#define NEGINF  (-3.0e38f)

typedef __attribute__((ext_vector_type(8))) short short8;
typedef __attribute__((ext_vector_type(4))) float f32x4;

// fp32 -> bf16 round-to-nearest-even
__device__ __forceinline__ unsigned short f2bf(float x) {
  union { float f; unsigned int u; } a; a.f = x;
  unsigned int r = (a.u + 0x7fffu + ((a.u >> 16) & 1u)) >> 16;
  return (unsigned short)r;
}

// async global->LDS DMA, 16 B per lane; LDS dst = wave-uniform base + lane*16
__device__ __forceinline__ void dma16(const void* g, void* l) {
  __builtin_amdgcn_global_load_lds(
      (const __attribute__((address_space(1))) unsigned int*)g,
      (__attribute__((address_space(3))) unsigned int*)l, 16, 0, 0);
}

// ---------------------------------------------------------------------------
// Kernel 0: query fp32 -> bf16, chunk-major + XOR-swizzled (16B blocks), qnorm
// layout: qbf[kc][m][ (blk ^ (m&7)) ]  with blk = 8-bf16 (16 B) blocks, 8/row
// ---------------------------------------------------------------------------
__global__ __launch_bounds__(256) void prep_kernel(
    const float* __restrict__ q, unsigned short* __restrict__ qbf,
    float* __restrict__ qnorm) {
  const int m = blockIdx.x;
  const int t = threadIdx.x;
  const f32x4 v = *(const f32x4*)(q + (size_t)m * DDIM + t * 4);
  const int k = t * 4;
  const int kc = k >> 6;
  const int jb = (k >> 3) & 7;
  const int half = (k >> 2) & 1;
  ushort4 h;
  h.x = f2bf(v.x); h.y = f2bf(v.y); h.z = f2bf(v.z); h.w = f2bf(v.w);
  *(ushort4*)(qbf + (size_t)kc * (MQ * BK) + m * 64 + ((jb ^ (m & 7)) * 8) + half * 4) = h;

  float ss = v.x * v.x + v.y * v.y + v.z * v.z + v.w * v.w;
  #pragma unroll
  for (int off = 1; off < 64; off <<= 1) ss += __shfl_xor(ss, off);
  __shared__ float red[4];
  if ((t & 63) == 0) red[t >> 6] = ss;
  __syncthreads();
  if (t == 0) qnorm[m] = sqrtf(red[0] + red[1] + red[2] + red[3]);
}

// ---------------------------------------------------------------------------
// Kernel 1: fused  dots = Q @ Mem^T  (bf16 MFMA) + mnorm + per-chunk argmax
// WG tile 256x64, wave tile 64x64 (4x4 of 16x16x32), K-loop BK=64
// ---------------------------------------------------------------------------
__global__ __launch_bounds__(THREADS, 3) void sim_argmax_kernel(
    const float* __restrict__ mem, const unsigned short* __restrict__ qbf,
    float* __restrict__ pmax, int* __restrict__ pidx) {
  __shared__ unsigned short As[MQ * BK];   // 32 KB, swizzled (DMA'd)
  __shared__ unsigned short Bs[NT * BK];   // 8 KB, swizzled
  __shared__ float rinv[NT];

  const int t = threadIdx.x;
  const int lane = t & 63;
  const int w = t >> 6;
  const int c = blockIdx.x;
  const int n0 = c * NT;

  const int br = t >> 2;   // B staging row 0..63 (fixed per thread across K)
  const int bj = t & 3;    // 4 threads per row

  f32x4 acc[4][4];
  #pragma unroll
  for (int mi = 0; mi < 4; ++mi)
    #pragma unroll
    for (int ni = 0; ni < 4; ++ni)
      acc[mi][ni] = (f32x4){0.f, 0.f, 0.f, 0.f};

  const bool browok = (n0 + br) < N_MEM;
  const float* browp = mem + (size_t)(n0 + br) * DDIM;
  float sumsq = 0.f;

  for (int kc = 0; kc < KCHUNKS; ++kc) {
    // ---- A tile: 32 KB DMA from pre-swizzled bf16 query ----
    const unsigned short* qc = qbf + (size_t)kc * (MQ * BK);
    #pragma unroll
    for (int i = 0; i < 8; ++i)
      dma16(qc + i * 2048 + t * 8, (void*)(As + i * 2048 + t * 8));

    // ---- B tile: fp32 load (64B-coalesced), cvt bf16, swizzled LDS write ----
    f32x4 v[4];
    const float* p = browp + kc * BK + bj * 4;
    #pragma unroll
    for (int i = 0; i < 4; ++i) {
      if (browok) v[i] = *(const f32x4*)(p + i * 16);
      else        v[i] = (f32x4){0.f, 0.f, 0.f, 0.f};
      sumsq += v[i].x * v[i].x + v[i].y * v[i].y + v[i].z * v[i].z + v[i].w * v[i].w;
      const int col = i * 16 + bj * 4;
      const int jb = col >> 3;
      const int half = (col >> 2) & 1;
      ushort4 h;
      h.x = f2bf(v[i].x); h.y = f2bf(v[i].y); h.z = f2bf(v[i].z); h.w = f2bf(v[i].w);
      *(ushort4*)(Bs + br * 64 + ((jb ^ (br & 7)) * 8) + half * 4) = h;
    }
    __syncthreads();   // waits DMA (vmcnt) + LDS writes

    // ---- MFMA: 2 K-steps x 16 MFMA, 8 ds_read_b128 per step ----
    {
      const int quad = lane >> 4, li = lane & 15;
      #pragma unroll
      for (int s = 0; s < 2; ++s) {
        const int kb = s * 4 + quad;
        short8 af[4], bfr[4];
        #pragma unroll
        for (int mi = 0; mi < 4; ++mi) {
          const int m = w * 64 + mi * 16 + li;
          af[mi] = *(const short8*)(As + m * 64 + ((kb ^ (m & 7)) * 8));
        }
        #pragma unroll
        for (int ni = 0; ni < 4; ++ni) {
          const int n = ni * 16 + li;
          bfr[ni] = *(const short8*)(Bs + n * 64 + ((kb ^ (n & 7)) * 8));
        }
        #pragma unroll
        for (int mi = 0; mi < 4; ++mi)
          #pragma unroll
          for (int ni = 0; ni < 4; ++ni)
            acc[mi][ni] = __builtin_amdgcn_mfma_f32_16x16x32_bf16(
                af[mi], bfr[ni], acc[mi][ni], 0, 0, 0);
      }
    }
    __syncthreads();   // before next staging overwrite
  }

  // ---- mnorm: reduce sumsq across the 4 staging threads of each row ----
  sumsq += __shfl_xor(sumsq, 1);
  sumsq += __shfl_xor(sumsq, 2);
  if (bj == 0) rinv[br] = browok ? rsqrtf(fmaxf(sumsq, 1e-30f)) : 0.f;
  __syncthreads();

  // ---- per-row argmax of dot/mnorm over this chunk's 64 cols ----
  {
    const int quad = lane >> 4, li = lane & 15;
    float rv[4]; int gn[4];
    #pragma unroll
    for (int ni = 0; ni < 4; ++ni) {
      const int nl = ni * 16 + li;
      rv[ni] = rinv[nl];
      gn[ni] = n0 + nl;
    }
    #pragma unroll
    for (int mi = 0; mi < 4; ++mi) {
      #pragma unroll
      for (int r = 0; r < 4; ++r) {
        float best = NEGINF; int bi = 0x7fffffff;
        #pragma unroll
        for (int ni = 0; ni < 4; ++ni) {
          float vv = acc[mi][ni][r] * rv[ni];
          vv = (gn[ni] < N_MEM) ? vv : NEGINF;
          if (vv > best || (vv == best && gn[ni] < bi)) { best = vv; bi = gn[ni]; }
        }
        #pragma unroll
        for (int off = 1; off < 16; off <<= 1) {
          const float ov = __shfl_xor(best, off);
          const int oi = __shfl_xor(bi, off);
          if (ov > best || (ov == best && oi < bi)) { best = ov; bi = oi; }
        }
        if (li == 0) {
          const int row = w * 64 + mi * 16 + quad * 4 + r;
          pmax[(size_t)c * MQ + row] = best;
          pidx[(size_t)c * MQ + row] = bi;
        }
      }
    }
  }
}

// ---------------------------------------------------------------------------
// Kernel 2: global argmax over 782 chunks, threshold, decode (or zeros)
// ---------------------------------------------------------------------------
__global__ __launch_bounds__(256) void finalize_kernel(
    const float* __restrict__ mem, const float* __restrict__ dec_w,
    const float* __restrict__ dec_b, const float* __restrict__ qnorm,
    const float* __restrict__ pmax, const int* __restrict__ pidx,
    float* __restrict__ out) {
  const int b = blockIdx.x;
  const int t = threadIdx.x;
  float best = NEGINF; int bi = 0x7fffffff;
  for (int c = t; c < NCHUNK; c += 256) {
    const float v = pmax[(size_t)c * MQ + b];
    const int i = pidx[(size_t)c * MQ + b];
    if (v > best || (v == best && i < bi)) { best = v; bi = i; }
  }
  #pragma unroll
  for (int off = 1; off < 64; off <<= 1) {
    const float ov = __shfl_xor(best, off);
    const int oi = __shfl_xor(bi, off);
    if (ov > best || (ov == best && oi < bi)) { best = ov; bi = oi; }
  }
  __shared__ float sv[4]; __shared__ int si[4];
  __shared__ float sbest; __shared__ int sbi;
  if ((t & 63) == 0) { sv[t >> 6] = best; si[t >> 6] = bi; }
  __syncthreads();
  if (t == 0) {
    float bb = sv[0]; int ii = si[0];
    #pragma unroll
    for (int k = 1; k < 4; ++k)
      if (sv[k] > bb || (sv[k] == bb && si[k] < ii)) { bb = sv[k]; ii = si[k]; }
    sbest = bb; sbi = ii;
  }
  __syncthreads();

  const float sim = sbest / fmaxf(qnorm[b], 1e-20f);  // sbest = dot/mnorm
  if (sim > SIM_TH) {
    __shared__ float ms[DDIM];
    *(f32x4*)(ms + t * 4) = *(const f32x4*)(mem + (size_t)sbi * DDIM + t * 4);
    __syncthreads();
    #pragma unroll
    for (int jj = 0; jj < 4; ++jj) {
      const int j = jj * 256 + t;
      const float* wr = dec_w + (size_t)j * DDIM;
      float s = dec_b[j];
      for (int k = 0; k < DDIM; k += 4) {
        const f32x4 a = *(const f32x4*)(ms + k);
        const f32x4 ww = *(const f32x4*)(wr + k);
        s += a.x * ww.x + a.y * ww.y + a.z * ww.z + a.w * ww.w;
      }
      out[(size_t)b * DDIM + j] = s;
    }
  } else {
    *(f32x4*)(out + (size_t)b * DDIM + t * 4) = (f32x4){0.f, 0.f, 0.f, 0.f};
  }
}

// ---------------------------------------------------------------------------
extern "C" void kernel_launch(void* const* d_in, const int* in_sizes, int n_in,
                              void* d_out, int out_size, void* d_ws, size_t ws_size,
                              hipStream_t stream) {
  const float* query = (const float*)d_in[0];   // [256,1024]
  const float* mem   = (const float*)d_in[1];   // [50000,1024]
  const float* dec_w = (const float*)d_in[2];   // [1024,1024]
  const float* dec_b = (const float*)d_in[3];   // [1024]
  float* out = (float*)d_out;                   // [256,1024]

  char* ws = (char*)d_ws;
  unsigned short* qbf = (unsigned short*)ws;                    // 512 KB
  float* qnorm = (float*)(ws + 524288);                         // 1 KB
  float* pmax  = (float*)(ws + 525312);                         // 782*256*4
  int*   pidx  = (int*)(ws + 525312 + (size_t)NCHUNK * MQ * 4); // 782*256*4

  hipLaunchKernelGGL(prep_kernel, dim3(MQ), dim3(256), 0, stream,
                     query, qbf, qnorm);
  hipLaunchKernelGGL(sim_argmax_kernel, dim3(NCHUNK), dim3(THREADS), 0, stream,
                     mem, qbf, pmax, pidx);
  hipLaunchKernelGGL(finalize_kernel, dim3(MQ), dim3(256), 0, stream,
                     mem, dec_w, dec_b, qnorm, pmax, pidx, out);
}